// Round 1
// 448.845 us; speedup vs baseline: 1.0207x; 1.0207x over previous
//
#include <hip/hip_runtime.h>
#include <math.h>

#define NH   8
#define HW   32
#define LSEQ 2048
#define EMB  256
#define BB   2

typedef short bf16x8 __attribute__((ext_vector_type(8)));
typedef float f32x4  __attribute__((ext_vector_type(4)));
typedef unsigned short u16x4 __attribute__((ext_vector_type(4)));

__device__ __forceinline__ unsigned short f2bf(float x) {  // RNE
  union { float f; unsigned u; } v; v.f = x;
  unsigned r = v.u + 0x7fffu + ((v.u >> 16) & 1u);
  return (unsigned short)(r >> 16);
}
__device__ __forceinline__ float bf2f(unsigned short h) {
  union { float f; unsigned u; } v; v.u = ((unsigned)h) << 16;
  return v.f;
}
__device__ __forceinline__ void split2(float x, unsigned short& h, unsigned short& l) {
  h = f2bf(x);
  l = f2bf(x - bf2f(h));
}

// ---------------------------------------------------------------------------
// One-shot RNE hi/lo bf16 pre-split of X, Wp, Wo.  Bit-identical to the
// inline split2 the GEMMs used to do (64x redundantly for W panels).
// Grid 1280 x 256 covers (4096*256 + 768*256 + 256*256)/4 float4 groups.
// ---------------------------------------------------------------------------
__global__ __launch_bounds__(256) void presplit(
    const float* __restrict__ X, const float* __restrict__ Wp,
    const float* __restrict__ Wo,
    unsigned short* __restrict__ Xh, unsigned short* __restrict__ Xl,
    unsigned short* __restrict__ Wph, unsigned short* __restrict__ Wpl,
    unsigned short* __restrict__ Woh, unsigned short* __restrict__ Wol) {
  const int NX = 4096 * 256, NP = 768 * 256, NO = 256 * 256;
  const int total4 = (NX + NP + NO) >> 2;
  int i4 = blockIdx.x * 256 + threadIdx.x;
  if (i4 >= total4) return;
  int e = i4 << 2;
  const float* src;
  unsigned short *dh, *dl;
  int off;
  if (e < NX)           { src = X;  dh = Xh;  dl = Xl;  off = e; }
  else if (e < NX + NP) { src = Wp; dh = Wph; dl = Wpl; off = e - NX; }
  else                  { src = Wo; dh = Woh; dl = Wol; off = e - NX - NP; }
  float4 v = *(const float4*)(src + off);
  u16x4 h, l;
  unsigned short hh, ll;
  split2(v.x, hh, ll); h[0] = hh; l[0] = ll;
  split2(v.y, hh, ll); h[1] = hh; l[1] = ll;
  split2(v.z, hh, ll); h[2] = hh; l[2] = ll;
  split2(v.w, hh, ll); h[3] = hh; l[3] = ll;
  *(u16x4*)(dh + off) = h;
  *(u16x4*)(dl + off) = l;
}

// ---------------------------------------------------------------------------
// QKV projection, split-bf16 MFMA, LDS-free, pre-split inputs.
// Block 256 thr = 4 waves stacked on m; wave = 16m x 64n; grid (12, 64).
// A = X[m][e] (lane: m=col, e=quad*8+j), B = Wp[f][e] (f=col) -> D[m][f].
// Outputs: Qh/Ql,Kh/Kl [b][h][l][32] (Q scaled), Vth/Vtl [b][h][c][2048].
// ---------------------------------------------------------------------------
__global__ __launch_bounds__(256, 4) void qkv_gemm(
    const unsigned short* __restrict__ Xh, const unsigned short* __restrict__ Xl,
    const unsigned short* __restrict__ Wph, const unsigned short* __restrict__ Wpl,
    unsigned short* __restrict__ Qh, unsigned short* __restrict__ Ql,
    unsigned short* __restrict__ Kh, unsigned short* __restrict__ Kl,
    unsigned short* __restrict__ Vth, unsigned short* __restrict__ Vtl) {
  const int t = threadIdx.x;
  const int w = t >> 6, lane = t & 63;
  const int col = lane & 15, quad = lane >> 4;
  const int m0 = blockIdx.y * 64 + w * 16;
  const int n0 = blockIdx.x * 64;
  const size_t xoff = (size_t)(m0 + col) * 256 + quad * 8;

  f32x4 acc[4];
#pragma unroll
  for (int nt = 0; nt < 4; ++nt) acc[nt] = (f32x4){0.f, 0.f, 0.f, 0.f};

#pragma unroll
  for (int es = 0; es < 8; ++es) {
    bf16x8 ah = *(const bf16x8*)(Xh + xoff + es * 32);
    bf16x8 al = *(const bf16x8*)(Xl + xoff + es * 32);
#pragma unroll
    for (int nt = 0; nt < 4; ++nt) {
      const size_t woff = (size_t)(n0 + nt * 16 + col) * 256 + es * 32 + quad * 8;
      bf16x8 bh = *(const bf16x8*)(Wph + woff);
      bf16x8 bl = *(const bf16x8*)(Wpl + woff);
      acc[nt] = __builtin_amdgcn_mfma_f32_16x16x32_bf16(ah, bh, acc[nt], 0, 0, 0);
      acc[nt] = __builtin_amdgcn_mfma_f32_16x16x32_bf16(ah, bl, acc[nt], 0, 0, 0);
      acc[nt] = __builtin_amdgcn_mfma_f32_16x16x32_bf16(al, bh, acc[nt], 0, 0, 0);
    }
  }

  const float qscale = 0.17677669529663687f;  // 32^-0.5
#pragma unroll
  for (int nt = 0; nt < 4; ++nt) {
    const int f = n0 + nt * 16 + col;
    const int hd = f / 96, r0 = f - hd * 96;
#pragma unroll
    for (int r = 0; r < 4; ++r) {
      const int m = m0 + quad * 4 + r;
      const int bbv = m >> 11, ll = m & 2047;
      float v = acc[nt][r];
      unsigned short hi, lo;
      if (r0 < 64) {
        float sv = (r0 < 32) ? v * qscale : v;
        split2(sv, hi, lo);
        size_t idx = ((size_t)(bbv * NH + hd) * LSEQ + ll) * HW + (r0 & 31);
        if (r0 < 32) { Qh[idx] = hi; Ql[idx] = lo; }
        else         { Kh[idx] = hi; Kl[idx] = lo; }
      } else {
        split2(v, hi, lo);
        size_t idx = ((size_t)(bbv * NH + hd) * HW + (r0 - 64)) * LSEQ + ll;
        Vth[idx] = hi; Vtl[idx] = lo;
      }
    }
  }
}

// ---------------------------------------------------------------------------
// MFMA flash attention with pair bias, k-split across blocks.
// Grid 512: p=(qt,b,ks) with hh-sibling (x^8) on same XCD for bias line share.
// Block 512 thr = 8 waves = 4 heads x 2 wks; block k-range 1024; 16 iters of
// 64-k tiles.  Bias tile staged to LDS [h][q][k] (coalesced float4 global
// loads, reg-prefetched 1 tile ahead); lane reads one ds_read_b128 -> used as
// MFMA C-initializer.  P-bounce: split BEFORE store, hi|lo packed in one
// dword (read side is 2 bit-ops/elem instead of a split2).  K/V global loads
// issued right after barrier1 so L2 latency hides under the Bst ds_writes.
// Partial (o,m,l) to workspace; merged in out_gemm.
// ---------------------------------------------------------------------------
__global__ __launch_bounds__(512, 4) void attn(
    const unsigned short* __restrict__ Qh, const unsigned short* __restrict__ Ql,
    const unsigned short* __restrict__ Kh, const unsigned short* __restrict__ Kl,
    const unsigned short* __restrict__ Vth, const unsigned short* __restrict__ Vtl,
    const float* __restrict__ Bias, float* __restrict__ Yp,
    float* __restrict__ Mm, float* __restrict__ Ll) {
  __shared__ __attribute__((aligned(16))) float Bst[4 * 32 * 72];       // 36.9KB
  __shared__ __attribute__((aligned(16))) unsigned Pbuf[8 * 1152];      // 36.9KB
  const int t = threadIdx.x;
  const int w = t >> 6, lane = t & 63;
  const int col = lane & 15, quad = lane >> 4;
  const int head = w >> 1, wks = w & 1;
  const int x = blockIdx.x;
  const int p = ((x >> 4) << 3) | (x & 7);
  const int hh = (x >> 3) & 1;
  const int ks = p & 1;
  const int b = (p >> 1) & 1;
  const int q0g = (p >> 2) * 32;
  const int hg = hh * 4 + head;
  const int kbase = ks * 1024;

  const size_t bhoff = (size_t)(b * NH + hg) * LSEQ * HW;
  const unsigned short* Qhp = Qh + bhoff;
  const unsigned short* Qlp = Ql + bhoff;
  const unsigned short* Khp = Kh + bhoff;
  const unsigned short* Klp = Kl + bhoff;
  const unsigned short* Vhp = Vth + bhoff;
  const unsigned short* Vlp = Vtl + bhoff;
  unsigned* Pw = &Pbuf[w * 1152];

  // Q B-frags (q=col, c=quad*8+j)
  bf16x8 Qbh[2], Qbl[2];
#pragma unroll
  for (int qt = 0; qt < 2; ++qt) {
    size_t off = (size_t)(q0g + qt * 16 + col) * HW + quad * 8;
    Qbh[qt] = *(const bf16x8*)(Qhp + off);
    Qbl[qt] = *(const bf16x8*)(Qlp + off);
  }

  f32x4 o[2][2];
#pragma unroll
  for (int ct = 0; ct < 2; ++ct)
#pragma unroll
    for (int qt = 0; qt < 2; ++qt) o[ct][qt] = (f32x4){0.f, 0.f, 0.f, 0.f};
  float m_i[2] = {-1e30f, -1e30f}, l_i[2] = {0.f, 0.f};

  // staging index (thread-uniform per u): q = u*8 + w, k = lane
  const int sq = w, sk = lane;
  // prefetch bias tile 0
  float4 bsr[4];
#pragma unroll
  for (int u = 0; u < 4; ++u)
    bsr[u] = *(const float4*)&Bias[(((size_t)(b * LSEQ + q0g + u * 8 + sq)) * LSEQ +
                                    kbase + sk) * NH + hh * 4];

#pragma unroll 1
  for (int it = 0; it < 16; ++it) {
    __syncthreads();  // prior reads of Bst done
    // K (A-frag: k=col) and V^T (A-frag: c=col) loads for this tile --
    // issued FIRST so their L2 latency hides under the Bst ds_writes.
    const int kw = kbase + it * 64 + wks * 32;
    bf16x8 Kah[2], Kal[2], Vah[2], Val[2];
#pragma unroll
    for (int kt = 0; kt < 2; ++kt) {
      size_t off = (size_t)(kw + kt * 16 + col) * HW + quad * 8;
      Kah[kt] = *(const bf16x8*)(Khp + off);
      Kal[kt] = *(const bf16x8*)(Klp + off);
    }
#pragma unroll
    for (int ct = 0; ct < 2; ++ct) {
      size_t off = (size_t)(ct * 16 + col) * LSEQ + kw + quad * 8;
      Vah[ct] = *(const bf16x8*)(Vhp + off);
      Val[ct] = *(const bf16x8*)(Vlp + off);
    }
#pragma unroll
    for (int u = 0; u < 4; ++u) {
      const int qq = u * 8 + sq;
      Bst[0 * 2304 + qq * 72 + sk] = bsr[u].x;
      Bst[1 * 2304 + qq * 72 + sk] = bsr[u].y;
      Bst[2 * 2304 + qq * 72 + sk] = bsr[u].z;
      Bst[3 * 2304 + qq * 72 + sk] = bsr[u].w;
    }
    if (it < 15) {
#pragma unroll
      for (int u = 0; u < 4; ++u)
        bsr[u] = *(const float4*)&Bias[(((size_t)(b * LSEQ + q0g + u * 8 + sq)) * LSEQ +
                                        kbase + (it + 1) * 64 + sk) * NH + hh * 4];
    }
    __syncthreads();  // Bst visible

    // S^T = K.Q^T with C initialized to bias (bias[q=col][k=quad*4+r])
    f32x4 s[2][2];
#pragma unroll
    for (int kt = 0; kt < 2; ++kt)
#pragma unroll
      for (int qt = 0; qt < 2; ++qt) {
        f32x4 a = *(const f32x4*)&Bst[head * 2304 + (qt * 16 + col) * 72 +
                                      wks * 32 + kt * 16 + quad * 4];
        a = __builtin_amdgcn_mfma_f32_16x16x32_bf16(Kah[kt], Qbh[qt], a, 0, 0, 0);
        a = __builtin_amdgcn_mfma_f32_16x16x32_bf16(Kah[kt], Qbl[qt], a, 0, 0, 0);
        a = __builtin_amdgcn_mfma_f32_16x16x32_bf16(Kal[kt], Qbh[qt], a, 0, 0, 0);
        s[kt][qt] = a;
      }

    // online softmax (row = q = col; spread over quads via xor 16/32)
    float alpha[2];
#pragma unroll
    for (int qt = 0; qt < 2; ++qt) {
      float mx = s[0][qt][0];
#pragma unroll
      for (int r = 1; r < 4; ++r) mx = fmaxf(mx, s[0][qt][r]);
#pragma unroll
      for (int r = 0; r < 4; ++r) mx = fmaxf(mx, s[1][qt][r]);
      mx = fmaxf(mx, __shfl_xor(mx, 16, 64));
      mx = fmaxf(mx, __shfl_xor(mx, 32, 64));
      float mnew = fmaxf(m_i[qt], mx);
      float al = __expf(m_i[qt] - mnew);
      float ps = 0.f;
#pragma unroll
      for (int kt = 0; kt < 2; ++kt)
#pragma unroll
        for (int r = 0; r < 4; ++r) {
          float pv = __expf(s[kt][qt][r] - mnew);
          s[kt][qt][r] = pv;
          ps += pv;
        }
      ps += __shfl_xor(ps, 16, 64);
      ps += __shfl_xor(ps, 32, 64);
      l_i[qt] = l_i[qt] * al + ps;
      m_i[qt] = mnew;
      alpha[qt] = al;
#pragma unroll
      for (int ct = 0; ct < 2; ++ct)
#pragma unroll
        for (int r = 0; r < 4; ++r) o[ct][qt][r] *= al;
    }

    // P bounce: split hi/lo BEFORE store, pack into one dword per element.
    // C-layout -> LDS (wave-private) -> B-frag (read side: 2 bit-ops/elem).
#pragma unroll
    for (int kt = 0; kt < 2; ++kt)
#pragma unroll
      for (int qt = 0; qt < 2; ++qt)
#pragma unroll
        for (int r = 0; r < 4; ++r) {
          unsigned short hi, lo; split2(s[kt][qt][r], hi, lo);
          Pw[(kt * 16 + quad * 4 + r) * 34 + qt * 16 + col] =
              (unsigned)hi | ((unsigned)lo << 16);
        }
    bf16x8 Pbh[2], Pbl[2];
#pragma unroll
    for (int qt = 0; qt < 2; ++qt) {
#pragma unroll
      for (int j = 0; j < 8; ++j) {
        unsigned d = Pw[(quad * 8 + j) * 34 + qt * 16 + col];
        Pbh[qt][j] = (short)(d & 0xffffu);
        Pbl[qt][j] = (short)(d >> 16);
      }
    }
    // O^T += V^T . P^T
#pragma unroll
    for (int ct = 0; ct < 2; ++ct)
#pragma unroll
      for (int qt = 0; qt < 2; ++qt) {
        f32x4 a = o[ct][qt];
        a = __builtin_amdgcn_mfma_f32_16x16x32_bf16(Vah[ct], Pbh[qt], a, 0, 0, 0);
        a = __builtin_amdgcn_mfma_f32_16x16x32_bf16(Vah[ct], Pbl[qt], a, 0, 0, 0);
        a = __builtin_amdgcn_mfma_f32_16x16x32_bf16(Val[ct], Pbh[qt], a, 0, 0, 0);
        o[ct][qt] = a;
      }
  }

  // ---- merge the two wks waves of each head; store partials ----
  __syncthreads();
  float* Pwf = (float*)Pw;
  if (wks == 1) {
#pragma unroll
    for (int ct = 0; ct < 2; ++ct)
#pragma unroll
      for (int qt = 0; qt < 2; ++qt)
#pragma unroll
        for (int r = 0; r < 4; ++r)
          Pwf[(ct * 16 + quad * 4 + r) * 34 + qt * 16 + col] = o[ct][qt][r];
    if (quad == 0) {
#pragma unroll
      for (int qt = 0; qt < 2; ++qt) {
        Pwf[1088 + qt * 16 + col] = m_i[qt];
        Pwf[1120 + qt * 16 + col] = l_i[qt];
      }
    }
  }
  __syncthreads();
  if (wks == 0) {
    const float* Pp = Pwf + 1152;  // partner (same head, wks=1)
#pragma unroll
    for (int qt = 0; qt < 2; ++qt) {
      float m2 = Pp[1088 + qt * 16 + col];
      float l2 = Pp[1120 + qt * 16 + col];
      float mm = fmaxf(m_i[qt], m2);
      float a1 = __expf(m_i[qt] - mm);
      float a2 = __expf(m2 - mm);
      float lm = l_i[qt] * a1 + l2 * a2;
      const size_t row = (size_t)ks * 4096 + b * LSEQ + q0g + qt * 16 + col;
      if (quad == 0) {
        Mm[row * 8 + hg] = mm;
        Ll[row * 8 + hg] = lm;
      }
#pragma unroll
      for (int ct = 0; ct < 2; ++ct) {
        float4 res;
        res.x = o[ct][qt][0] * a1 + Pp[(ct * 16 + quad * 4 + 0) * 34 + qt * 16 + col] * a2;
        res.y = o[ct][qt][1] * a1 + Pp[(ct * 16 + quad * 4 + 1) * 34 + qt * 16 + col] * a2;
        res.z = o[ct][qt][2] * a1 + Pp[(ct * 16 + quad * 4 + 2) * 34 + qt * 16 + col] * a2;
        res.w = o[ct][qt][3] * a1 + Pp[(ct * 16 + quad * 4 + 3) * 34 + qt * 16 + col] * a2;
        *(float4*)&Yp[row * EMB + hg * HW + ct * 16 + quad * 4] = res;
      }
    }
  }
}

// ---------------------------------------------------------------------------
// Output projection with fused k-split merge.  Split-bf16 MFMA, LDS-free,
// pre-split Wo.  Block 256 = 4 waves on m; wave 16m x 64n; grid (4, 64).
// A[m][e] = merged y (from Yp/Mm/Ll partials, computed on the fly);
// B[f][e] = Wo.  Out += bo.
// ---------------------------------------------------------------------------
__global__ __launch_bounds__(256, 4) void out_gemm(
    const float* __restrict__ Yp, const float* __restrict__ Mm,
    const float* __restrict__ Ll, const unsigned short* __restrict__ Woh,
    const unsigned short* __restrict__ Wol, const float* __restrict__ bo,
    float* __restrict__ Out) {
  const int t = threadIdx.x;
  const int w = t >> 6, lane = t & 63;
  const int col = lane & 15, quad = lane >> 4;
  const int m0 = blockIdx.y * 64 + w * 16;
  const int n0 = blockIdx.x * 64;
  const int grow = m0 + col;
  const float* o1p = Yp + (size_t)grow * 256 + quad * 8;
  const float* o2p = o1p + (size_t)4096 * 256;

  // vectorized merge-stat loads (8 float4 instead of 32 scalars)
  float m1v[8], l1v[8], m2v[8], l2v[8];
  *(float4*)&m1v[0] = *(const float4*)&Mm[(size_t)grow * 8];
  *(float4*)&m1v[4] = *(const float4*)&Mm[(size_t)grow * 8 + 4];
  *(float4*)&l1v[0] = *(const float4*)&Ll[(size_t)grow * 8];
  *(float4*)&l1v[4] = *(const float4*)&Ll[(size_t)grow * 8 + 4];
  *(float4*)&m2v[0] = *(const float4*)&Mm[(size_t)(4096 + grow) * 8];
  *(float4*)&m2v[4] = *(const float4*)&Mm[(size_t)(4096 + grow) * 8 + 4];
  *(float4*)&l2v[0] = *(const float4*)&Ll[(size_t)(4096 + grow) * 8];
  *(float4*)&l2v[4] = *(const float4*)&Ll[(size_t)(4096 + grow) * 8 + 4];

  f32x4 acc[4];
#pragma unroll
  for (int nt = 0; nt < 4; ++nt) acc[nt] = (f32x4){0.f, 0.f, 0.f, 0.f};

#pragma unroll
  for (int es = 0; es < 8; ++es) {  // es == head
    float M = fmaxf(m1v[es], m2v[es]);
    float w1 = __expf(m1v[es] - M), w2 = __expf(m2v[es] - M);
    float inv = 1.0f / (l1v[es] * w1 + l2v[es] * w2);
    w1 *= inv; w2 *= inv;
    float4 a1 = *(const float4*)(o1p + es * 32);
    float4 b1 = *(const float4*)(o1p + es * 32 + 4);
    float4 a2 = *(const float4*)(o2p + es * 32);
    float4 b2 = *(const float4*)(o2p + es * 32 + 4);
    float yv[8] = {a1.x * w1 + a2.x * w2, a1.y * w1 + a2.y * w2,
                   a1.z * w1 + a2.z * w2, a1.w * w1 + a2.w * w2,
                   b1.x * w1 + b2.x * w2, b1.y * w1 + b2.y * w2,
                   b1.z * w1 + b2.z * w2, b1.w * w1 + b2.w * w2};
    bf16x8 ah, al;
#pragma unroll
    for (int j = 0; j < 8; ++j) {
      unsigned short hi, lo; split2(yv[j], hi, lo);
      ah[j] = (short)hi; al[j] = (short)lo;
    }
#pragma unroll
    for (int nt = 0; nt < 4; ++nt) {
      const size_t woff = (size_t)(n0 + nt * 16 + col) * 256 + es * 32 + quad * 8;
      bf16x8 bh = *(const bf16x8*)(Woh + woff);
      bf16x8 bl = *(const bf16x8*)(Wol + woff);
      acc[nt] = __builtin_amdgcn_mfma_f32_16x16x32_bf16(ah, bh, acc[nt], 0, 0, 0);
      acc[nt] = __builtin_amdgcn_mfma_f32_16x16x32_bf16(ah, bl, acc[nt], 0, 0, 0);
      acc[nt] = __builtin_amdgcn_mfma_f32_16x16x32_bf16(al, bh, acc[nt], 0, 0, 0);
    }
  }
#pragma unroll
  for (int nt = 0; nt < 4; ++nt) {
    const int f = n0 + nt * 16 + col;
    const float bias_o = bo[f];
#pragma unroll
    for (int r = 0; r < 4; ++r)
      Out[(size_t)(m0 + quad * 4 + r) * 256 + f] = acc[nt][r] + bias_o;
  }
}

extern "C" void kernel_launch(void* const* d_in, const int* in_sizes, int n_in,
                              void* d_out, int out_size, void* d_ws, size_t ws_size,
                              hipStream_t stream) {
  const float* X    = (const float*)d_in[0];
  const float* Bias = (const float*)d_in[1];
  const float* Wp   = (const float*)d_in[2];
  const float* Wo   = (const float*)d_in[3];
  const float* bo   = (const float*)d_in[4];
  float* Out = (float*)d_out;

  const size_t qkv_elems = (size_t)BB * NH * LSEQ * HW;  // 1,048,576
  unsigned short* Qh  = (unsigned short*)d_ws;
  unsigned short* Ql  = Qh + qkv_elems;
  unsigned short* Kh  = Ql + qkv_elems;
  unsigned short* Kl  = Kh + qkv_elems;
  unsigned short* Vth = Kl + qkv_elems;
  unsigned short* Vtl = Vth + qkv_elems;
  float* Yp = (float*)(Vtl + qkv_elems);     // [2ks][4096][256] fp32 = 8 MB
  float* Mm = Yp + (size_t)2 * 4096 * 256;   // [2ks][4096][8]
  float* Ll = Mm + (size_t)2 * 4096 * 8;     // [2ks][4096][8]
  unsigned short* Xh  = (unsigned short*)(Ll + (size_t)2 * 4096 * 8);
  unsigned short* Xl  = Xh  + (size_t)4096 * 256;
  unsigned short* Wph = Xl  + (size_t)4096 * 256;
  unsigned short* Wpl = Wph + (size_t)768 * 256;
  unsigned short* Woh = Wpl + (size_t)768 * 256;
  unsigned short* Wol = Woh + (size_t)256 * 256;

  presplit<<<dim3(1280), 256, 0, stream>>>(X, Wp, Wo, Xh, Xl, Wph, Wpl, Woh, Wol);
  qkv_gemm<<<dim3(12, 64), 256, 0, stream>>>(Xh, Xl, Wph, Wpl, Qh, Ql, Kh, Kl, Vth, Vtl);
  attn<<<dim3(512), 512, 0, stream>>>(Qh, Ql, Kh, Kl, Vth, Vtl, Bias, Yp, Mm, Ll);
  out_gemm<<<dim3(4, 64), 256, 0, stream>>>(Yp, Mm, Ll, Woh, Wol, bo, Out);
}